// Round 2
// baseline (368.525 us; speedup 1.0000x reference)
//
#include <hip/hip_runtime.h>
#include <math.h>

// Problem constants (from reference): B=64, S=4096, D=256
#define B_   64
#define S_   4096
#define D_   256
#define CH   32                          // chunks per batch (split-softmax partials)
#define ROWS_PER_CHUNK (S_ / CH)         // 128
#define NWAVE 4
#define RPW   8                          // rows per wave per iteration (8 lanes per row)
#define ROWS_PER_BLOCK_ITER (NWAVE * RPW)             // 32
#define NITER (ROWS_PER_CHUNK / ROWS_PER_BLOCK_ITER)  // 4
#define LN_EPS 1e-3f

typedef float f4 __attribute__((ext_vector_type(4)));

// R6 change: PLAIN loads for x (was __builtin_nontemporal_load).
// Evidence: R0 (16-lane teams, NITER=8) and R5 (8-lane teams, NITER=4) measured
// 343.0 vs 343.58 us — structure-insensitive. rocprof top-5 shows pass1 does
// NOT outrank the harness's 1-GiB 164us fills => pass1 < 160us; the shared cap
// is not VALU/shuffle structure. Both kernels nt-load x. x = 268 MB is re-read
// EVERY bench iteration and nearly fits the 256 MiB L3; nt (evict-first) kills
// inter-iteration L3 residency and forces full-HBM re-reads. Plain loads keep
// ~95% of x L3-resident.
// Predicted: pass1 FETCH_SIZE drops ~10x, pass1 dur -> 40-60us.
//
// NOTE (R3 lesson, kept): do NOT fuse the merge with per-block __threadfence() —
// agent-scope fences emit buffer_wbl2 (L2 writeback) per block; 2048 blocks
// serialize on L2 coherence traffic => 530 µs kernel at 3% HBM BW.
__global__ __launch_bounds__(256) void pool_pass1(
    const float* __restrict__ x, const float* __restrict__ mask,
    const float* __restrict__ gamma, const float* __restrict__ w,
    float* __restrict__ ws_acc, float* __restrict__ ws_m, float* __restrict__ ws_l)
{
    const int blk   = blockIdx.x;
    const int b     = blk / CH;
    const int chunk = blk % CH;
    const int tid   = threadIdx.x;
    const int lane  = tid & 63;
    const int wave  = tid >> 6;
    const int o     = lane >> 3;   // octet: which of 8 rows this lane works on
    const int t     = lane & 7;    // sublane within the row's 8-lane team

    // gamma*w for this lane's 32 features (beta & dense-bias cancel in softmax)
    f4 gw[8];
    float sgw = 0.0f;
    #pragma unroll
    for (int k = 0; k < 8; ++k) {
        const int d = t * 4 + 32 * k;
        const f4 g4 = *(const f4*)(gamma + d);
        const f4 w4 = *(const f4*)(w + d);
        gw[k] = g4 * w4;
        sgw += gw[k][0] + gw[k][1] + gw[k][2] + gw[k][3];
    }
    #pragma unroll
    for (int off = 4; off > 0; off >>= 1) sgw += __shfl_xor(sgw, off, 64);

    // this lane's row at iteration i: chunk*128 + i*32 + wave*8 + o
    const int row0 = chunk * ROWS_PER_CHUNK + wave * RPW + o;
    const float* xbase = x + ((size_t)b * S_ + row0) * D_ + t * 4;
    const float* mbase = mask + (size_t)b * S_ + row0;

    float m = -3.0e38f;
    float l = 0.0f;
    f4 acc[8];
    #pragma unroll
    for (int k = 0; k < 8; ++k) acc[k] = (f4)0.0f;

    // depth-1 prefetch: 8 KiB of row data in flight across the reduce/softmax.
    // PLAIN loads (R6): keep x L3-resident across bench iterations.
    f4 v[8];
    #pragma unroll
    for (int k = 0; k < 8; ++k)
        v[k] = *(const f4*)(xbase + 32 * k);
    float msk = mbase[0];

    for (int i = 0; i < NITER; ++i) {
        const int inx = (i + 1 < NITER) ? i + 1 : i;
        f4 vn[8];
        #pragma unroll
        for (int k = 0; k < 8; ++k)
            vn[k] = *(const f4*)(xbase + (size_t)inx * ROWS_PER_BLOCK_ITER * D_ + 32 * k);
        const float mskn = mbase[inx * ROWS_PER_BLOCK_ITER];

        // three row reductions over the same data: sum, sumsq, dot(gamma*w)
        float s1 = 0.f, s2 = 0.f, s3 = 0.f;
        #pragma unroll
        for (int k = 0; k < 8; ++k) {
            #pragma unroll
            for (int j = 0; j < 4; ++j) {
                const float e = v[k][j];
                s1 += e;
                s2 += e * e;
                s3 += e * gw[k][j];
            }
        }
        // 3-round butterfly within the 8-lane team (s1,s2,s3 pipeline per round)
        #pragma unroll
        for (int off = 4; off > 0; off >>= 1) {
            s1 += __shfl_xor(s1, off, 64);
            s2 += __shfl_xor(s2, off, 64);
            s3 += __shfl_xor(s3, off, 64);
        }
        const float mu    = s1 * (1.0f / D_);
        const float var   = s2 * (1.0f / D_) - mu * mu;
        const float rstd  = rsqrtf(var + LN_EPS);
        const float score = rstd * (s3 - mu * sgw) + (1.0f - msk) * -1e9f;

        // online softmax update (identical within each 8-lane team)
        const float mnew  = fmaxf(m, score);
        const float scale = __expf(m - mnew);
        const float p     = __expf(score - mnew);
        m = mnew;
        l = l * scale + p;
        #pragma unroll
        for (int k = 0; k < 8; ++k) acc[k] = acc[k] * scale + p * v[k];

        #pragma unroll
        for (int k = 0; k < 8; ++k) v[k] = vn[k];
        msk = mskn;
    }

    // combine the 32 row-groups' partials in LDS
    __shared__ float s_acc[ROWS_PER_BLOCK_ITER][D_];  // 32 KiB
    __shared__ float s_m[ROWS_PER_BLOCK_ITER];
    __shared__ float s_l[ROWS_PER_BLOCK_ITER];
    const int g = wave * RPW + o;
    #pragma unroll
    for (int k = 0; k < 8; ++k) *(f4*)&s_acc[g][t * 4 + 32 * k] = acc[k];
    if (t == 0) { s_m[g] = m; s_l[g] = l; }
    __syncthreads();

    float M = -3.0e38f;
    #pragma unroll
    for (int gg = 0; gg < ROWS_PER_BLOCK_ITER; ++gg) M = fmaxf(M, s_m[gg]);
    float L = 0.f, a = 0.f;
    #pragma unroll
    for (int gg = 0; gg < ROWS_PER_BLOCK_ITER; ++gg) {
        const float e = __expf(s_m[gg] - M);
        L += e * s_l[gg];
        a += e * s_acc[gg][tid];
    }
    ws_acc[(size_t)blk * D_ + tid] = a;
    if (tid == 0) { ws_m[blk] = M; ws_l[blk] = L; }
}

// Pass 2: merge the CH partials per batch. One block per batch, one thread per d.
__global__ __launch_bounds__(256) void pool_pass2(
    const float* __restrict__ ws_acc, const float* __restrict__ ws_m,
    const float* __restrict__ ws_l, float* __restrict__ out)
{
    const int b = blockIdx.x;
    const int d = threadIdx.x;

    float M = -3.0e38f;
    #pragma unroll
    for (int c = 0; c < CH; ++c) M = fmaxf(M, ws_m[b * CH + c]);

    float L = 0.0f, a = 0.0f;
    #pragma unroll
    for (int c = 0; c < CH; ++c) {
        const float e = __expf(ws_m[b * CH + c] - M);
        L += e * ws_l[b * CH + c];
        a += e * ws_acc[((size_t)(b * CH + c)) * D_ + d];
    }
    out[(size_t)b * D_ + d] = a / L;
}

extern "C" void kernel_launch(void* const* d_in, const int* in_sizes, int n_in,
                              void* d_out, int out_size, void* d_ws, size_t ws_size,
                              hipStream_t stream) {
    // setup_inputs order: x, mask, gamma, beta, w, b
    const float* x     = (const float*)d_in[0];
    const float* mask  = (const float*)d_in[1];
    const float* gamma = (const float*)d_in[2];
    // d_in[3] = beta : cancels in softmax, unused
    const float* w     = (const float*)d_in[4];
    // d_in[5] = b    : cancels in softmax, unused
    float* out = (float*)d_out;

    // workspace layout: acc[B*CH*D] | m[B*CH] | l[B*CH]  (~2.02 MB)
    float* ws_acc = (float*)d_ws;
    float* ws_m   = ws_acc + (size_t)B_ * CH * D_;
    float* ws_l   = ws_m + B_ * CH;

    pool_pass1<<<B_ * CH, 256, 0, stream>>>(x, mask, gamma, w, ws_acc, ws_m, ws_l);
    pool_pass2<<<B_, 256, 0, stream>>>(ws_acc, ws_m, ws_l, out);
}

// Round 3
// 344.746 us; speedup vs baseline: 1.0690x; 1.0690x over previous
//
#include <hip/hip_runtime.h>
#include <math.h>

// Problem constants (from reference): B=64, S=4096, D=256
#define B_   64
#define S_   4096
#define D_   256
#define CH   32                          // chunks per batch (split-softmax partials)
#define ROWS_PER_CHUNK (S_ / CH)         // 128
#define NWAVE 4
#define ROWS_PER_BLOCK_ITER (NWAVE * 4)  // 16 (4 rows per wave, 16-lane teams)
#define NITER (ROWS_PER_CHUNK / ROWS_PER_BLOCK_ITER)  // 8
#define LN_EPS 1e-3f

typedef float f4 __attribute__((ext_vector_type(4)));

// R7: break the 64 KiB/CU in-flight invariant.
// Evidence so far: R0 (16-lane, depth-1, 4 w/SIMD) and R5 (8-lane, depth-1,
// 2 w/SIMD) both = 343 us — BUT both have exactly 64 KiB/CU of loads in
// flight (waves x prefetch-bytes invariant). nt->plain = +25 us => the x load
// path IS on the critical path; the 1 GiB harness poison fill flushes L3
// every iteration so residency games are dead (R6 lesson).
// This version: 16-lane teams (~125 VGPR -> 4 waves/SIMD) + DEPTH-2 prefetch
// via 3-slot rotating buffer (fully unrolled => static slot indices, no
// scratch) = 128 KiB/CU in flight, 2x all previous variants. Masks hoisted.
// Predicted: if MLP-bound, dur 343 -> ~300. If identical again, pass1 is at
// its floor and the harness fill dominates => roofline call next round.
//
// NOTE (R3 lesson, kept): do NOT fuse the merge with per-block __threadfence() —
// agent-scope fences emit buffer_wbl2 (L2 writeback) per block; 2048 blocks
// serialize on L2 coherence traffic => 530 µs kernel at 3% HBM BW.
__global__ __launch_bounds__(256) void pool_pass1(
    const float* __restrict__ x, const float* __restrict__ mask,
    const float* __restrict__ gamma, const float* __restrict__ w,
    float* __restrict__ ws_acc, float* __restrict__ ws_m, float* __restrict__ ws_l)
{
    const int blk   = blockIdx.x;
    const int b     = blk / CH;
    const int chunk = blk % CH;
    const int tid   = threadIdx.x;
    const int lane  = tid & 63;
    const int wave  = tid >> 6;
    const int q     = lane >> 4;   // quarter: which of 4 rows this lane works on
    const int t     = lane & 15;   // sublane within the row's 16-lane team

    // gamma*w for this lane's 16 features (beta & dense-bias cancel in softmax)
    f4 gw[4];
    float sgw = 0.0f;
    #pragma unroll
    for (int k = 0; k < 4; ++k) {
        const int d = t * 4 + 64 * k;
        const f4 g4 = *(const f4*)(gamma + d);
        const f4 w4 = *(const f4*)(w + d);
        gw[k] = g4 * w4;
        sgw += gw[k][0] + gw[k][1] + gw[k][2] + gw[k][3];
    }
    #pragma unroll
    for (int off = 8; off > 0; off >>= 1) sgw += __shfl_xor(sgw, off, 64);

    // this lane's row at iteration i: chunk*128 + i*16 + wave*4 + q
    const int row0 = chunk * ROWS_PER_CHUNK + wave * 4 + q;
    const float* xbase = x + ((size_t)b * S_ + row0) * D_ + t * 4;
    const float* mbase = mask + (size_t)b * S_ + row0;

    // hoist all 8 per-iteration mask values (tiny, 8 VGPR, issued early)
    float mk[NITER];
    #pragma unroll
    for (int i = 0; i < NITER; ++i)
        mk[i] = mbase[i * ROWS_PER_BLOCK_ITER];

    float m = -3.0e38f;
    float l = 0.0f;
    f4 acc[4];
    #pragma unroll
    for (int k = 0; k < 4; ++k) acc[k] = (f4)0.0f;

    // depth-2 prefetch: 3-slot rotating buffer, 8 KiB/wave in flight.
    // x is read exactly once per pass and L3 is flushed by the harness fill ->
    // non-temporal (evict-first) loads; plain loads measured +25 us (R6).
    f4 buf[3][4];
    #pragma unroll
    for (int s = 0; s < 2; ++s)
        #pragma unroll
        for (int k = 0; k < 4; ++k)
            buf[s][k] = __builtin_nontemporal_load(
                (const f4*)(xbase + (size_t)s * ROWS_PER_BLOCK_ITER * D_ + 64 * k));

    #pragma unroll
    for (int i = 0; i < NITER; ++i) {
        // prefetch iteration i+2 into the slot freed two iterations ago
        const int ipf = (i + 2 < NITER) ? i + 2 : NITER - 1;
        #pragma unroll
        for (int k = 0; k < 4; ++k)
            buf[(i + 2) % 3][k] = __builtin_nontemporal_load(
                (const f4*)(xbase + (size_t)ipf * ROWS_PER_BLOCK_ITER * D_ + 64 * k));

        const f4* v = buf[i % 3];

        // three row reductions over the same data: sum, sumsq, dot(gamma*w)
        float s1 = 0.f, s2 = 0.f, s3 = 0.f;
        #pragma unroll
        for (int k = 0; k < 4; ++k) {
            #pragma unroll
            for (int j = 0; j < 4; ++j) {
                const float e = v[k][j];
                s1 += e;
                s2 += e * e;
                s3 += e * gw[k][j];
            }
        }
        // 4-round butterfly within the 16-lane team (3 sums pipelined per round)
        #pragma unroll
        for (int off = 8; off > 0; off >>= 1) {
            s1 += __shfl_xor(s1, off, 64);
            s2 += __shfl_xor(s2, off, 64);
            s3 += __shfl_xor(s3, off, 64);
        }
        const float mu    = s1 * (1.0f / D_);
        const float var   = s2 * (1.0f / D_) - mu * mu;
        const float rstd  = rsqrtf(var + LN_EPS);
        const float score = rstd * (s3 - mu * sgw) + (1.0f - mk[i]) * -1e9f;

        // online softmax update (identical within each 16-lane team)
        const float mnew  = fmaxf(m, score);
        const float scale = __expf(m - mnew);
        const float p     = __expf(score - mnew);
        m = mnew;
        l = l * scale + p;
        #pragma unroll
        for (int k = 0; k < 4; ++k) acc[k] = acc[k] * scale + p * v[k];
    }

    // combine the 16 row-groups' partials in LDS
    __shared__ float s_acc[ROWS_PER_BLOCK_ITER][D_];  // 16 KiB
    __shared__ float s_m[ROWS_PER_BLOCK_ITER];
    __shared__ float s_l[ROWS_PER_BLOCK_ITER];
    const int g = wave * 4 + q;
    #pragma unroll
    for (int k = 0; k < 4; ++k) *(f4*)&s_acc[g][t * 4 + 64 * k] = acc[k];
    if (t == 0) { s_m[g] = m; s_l[g] = l; }
    __syncthreads();

    float M = -3.0e38f;
    #pragma unroll
    for (int gg = 0; gg < ROWS_PER_BLOCK_ITER; ++gg) M = fmaxf(M, s_m[gg]);
    float L = 0.f, a = 0.f;
    #pragma unroll
    for (int gg = 0; gg < ROWS_PER_BLOCK_ITER; ++gg) {
        const float e = __expf(s_m[gg] - M);
        L += e * s_l[gg];
        a += e * s_acc[gg][tid];
    }
    ws_acc[(size_t)blk * D_ + tid] = a;
    if (tid == 0) { ws_m[blk] = M; ws_l[blk] = L; }
}

// Pass 2: merge the CH partials per batch. One block per batch, one thread per d.
__global__ __launch_bounds__(256) void pool_pass2(
    const float* __restrict__ ws_acc, const float* __restrict__ ws_m,
    const float* __restrict__ ws_l, float* __restrict__ out)
{
    const int b = blockIdx.x;
    const int d = threadIdx.x;

    float M = -3.0e38f;
    #pragma unroll
    for (int c = 0; c < CH; ++c) M = fmaxf(M, ws_m[b * CH + c]);

    float L = 0.0f, a = 0.0f;
    #pragma unroll
    for (int c = 0; c < CH; ++c) {
        const float e = __expf(ws_m[b * CH + c] - M);
        L += e * ws_l[b * CH + c];
        a += e * ws_acc[((size_t)(b * CH + c)) * D_ + d];
    }
    out[(size_t)b * D_ + d] = a / L;
}

extern "C" void kernel_launch(void* const* d_in, const int* in_sizes, int n_in,
                              void* d_out, int out_size, void* d_ws, size_t ws_size,
                              hipStream_t stream) {
    // setup_inputs order: x, mask, gamma, beta, w, b
    const float* x     = (const float*)d_in[0];
    const float* mask  = (const float*)d_in[1];
    const float* gamma = (const float*)d_in[2];
    // d_in[3] = beta : cancels in softmax, unused
    const float* w     = (const float*)d_in[4];
    // d_in[5] = b    : cancels in softmax, unused
    float* out = (float*)d_out;

    // workspace layout: acc[B*CH*D] | m[B*CH] | l[B*CH]  (~2.02 MB)
    float* ws_acc = (float*)d_ws;
    float* ws_m   = ws_acc + (size_t)B_ * CH * D_;
    float* ws_l   = ws_m + B_ * CH;

    pool_pass1<<<B_ * CH, 256, 0, stream>>>(x, mask, gamma, w, ws_acc, ws_m, ws_l);
    pool_pass2<<<B_, 256, 0, stream>>>(ws_acc, ws_m, ws_l, out);
}